// Round 14
// baseline (37.840 us; speedup 1.0000x reference)
//
#include <hip/hip_runtime.h>
#include <hip/hip_bf16.h>

constexpr int NROWS = 8192;

typedef __attribute__((ext_vector_type(8))) short short8v; // 8 bf16
typedef __attribute__((ext_vector_type(4))) float f32x4;   // MFMA acc

__device__ __forceinline__ unsigned cvt2(float lo, float hi) {
    __hip_bfloat162 h;
    h.x = __float2bfloat16(lo);
    h.y = __float2bfloat16(hi);
    union { __hip_bfloat162 h2; unsigned u; } cv; cv.h2 = h; return cv.u;
}
__device__ __forceinline__ unsigned short f2bfu(float x) {
    __hip_bfloat16 h = __float2bfloat16(x);
    union { __hip_bfloat16 b; unsigned short u; } cv; cv.b = h; return cv.u;
}
// async global->LDS, 16B per lane; LDS dest must be linear (base + lane*16)
__device__ __forceinline__ void gload16(const void* g, void* l) {
    __builtin_amdgcn_global_load_lds(
        (const __attribute__((address_space(1))) unsigned int*)g,
        (__attribute__((address_space(3))) unsigned int*)l,
        16, 0, 0);
}

// ---------------------------------------------------------------------------
// Prep: 4 weight matrices -> bf16, once.  (proven)
// ---------------------------------------------------------------------------
__global__ __launch_bounds__(256) void prep_kernel(
    const float* __restrict__ Wq, const float* __restrict__ Wk,
    const float* __restrict__ Wv, const float* __restrict__ Wp,
    unsigned short* __restrict__ out)
{
    const float* srcs[4] = {Wq, Wk, Wv, Wp};
    const float* s = srcs[blockIdx.y];
    unsigned short* d = out + (size_t)blockIdx.y * 65536;
    int idx = blockIdx.x * 256 + threadIdx.x;
    float4 a = ((const float4*)s)[idx * 2];
    float4 b = ((const float4*)s)[idx * 2 + 1];
    uint4 p;
    p.x = cvt2(a.x, a.y); p.y = cvt2(a.z, a.w);
    p.z = cvt2(b.x, b.y); p.w = cvt2(b.z, b.w);
    ((uint4*)d)[idx] = p;
}

// ---------------------------------------------------------------------------
// Fully-fused kernel v3: R12 structure tiled for occupancy.
// 512 blocks x 16 rows x 256 threads; BK=32 -> LDS 35840 B -> 4 blocks/CU
// (16 waves/CU). Phases: kv GEMM (16 chunks) -> k,v->LDS + moments ->
// q GEMM (16 chunks, x = N/D in-register -> Xs) -> proj GEMM (4ng x 4c).
// All staging: dbuf gload_lds with XOR(row&3) swizzle (64B rows); A reg-staged.
// Zero intermediate global traffic.
// ---------------------------------------------------------------------------
__global__ __launch_bounds__(256, 4) void fused_kernel(
    const float* __restrict__ xq, const float* __restrict__ xkv,
    const unsigned short* __restrict__ Wbf,
    const float* __restrict__ bq, const float* __restrict__ bk,
    const float* __restrict__ bv, const float* __restrict__ pb,
    float* __restrict__ out)
{
    __shared__ __align__(16) char smem[35840];
    // 0     : As[2][16*40] bf16 A dbuf (2560 B)
    // 2560  : BsA[2][128*32] bf16 (16384 B)       Wk / Wq / Wp dbuf
    // 18944 : BsB[2][128*32] bf16 (16384 B)       Wv dbuf
    //         overlay after kv: k_lds[16][128] f32 (8192) @18944,
    //                           v_lds[16][128] f32 (8192) @27136
    //         overlay after moments: Xs[16*128] bf16 (4096) @18944
    // 35328 : mom[16][8] f32 (512 B)
    unsigned short (*As)[640]   = (unsigned short (*)[640])smem;
    unsigned short (*BsA)[4096] = (unsigned short (*)[4096])(smem + 2560);
    unsigned short (*BsB)[4096] = (unsigned short (*)[4096])(smem + 18944);
    float* k_lds = (float*)(smem + 18944);
    float* v_lds = (float*)(smem + 27136);
    unsigned short* Xs = (unsigned short*)(smem + 18944);
    float* momp = (float*)(smem + 35328);

    const int m0 = blockIdx.x * 16;
    const int tid = threadIdx.x, lane = tid & 63;
    const int wv = tid >> 6;                    // wave -> col group wv*32
    const int arow = tid >> 4, ac2 = tid & 15;  // A stage: row, float2-unit
    const int brow = tid >> 2, bu0 = tid & 3;   // B stage: row base, 16B-unit
    const int frow = lane & 15, t16 = lane >> 4;
    const int col_l = frow, row_l = t16 * 4;

    const unsigned short* Wqb = Wbf;
    const unsigned short* Wkb = Wbf + 65536;
    const unsigned short* Wvb = Wbf + 2 * 65536;
    const unsigned short* Wpb = Wbf + 3 * 65536;

    float2 ra;

#define LDA(src, c) ra = *(const float2*)((src) + (size_t)(m0 + arow) * 512 + (c) * 32 + ac2 * 2);
#define STA(buf) { unsigned p = cvt2(ra.x, ra.y); \
                   *(unsigned*)(&As[buf][arow * 40 + ac2 * 2]) = p; }
    // B stage: 128 rows x 32 k bf16 (64B/row, 4x16B units), swizzled src,
    // linear LDS dest. 2 gload16 per thread.
#define STB(Wm, Bsx, c, buf) { _Pragma("unroll") for (int i = 0; i < 2; ++i) { \
      int row = brow + i * 64; int su = bu0 ^ (row & 3); \
      gload16((Wm) + (size_t)row * 512 + (c) * 32 + su * 8, \
              &(Bsx)[buf][(row * 4 + bu0) * 8]); } }
#define STBP(ng, c, buf) { _Pragma("unroll") for (int i = 0; i < 2; ++i) { \
      int row = brow + i * 64; int su = bu0 ^ (row & 3); \
      gload16(Wpb + (size_t)((ng) * 128 + row) * 128 + (c) * 32 + su * 8, \
              &BsA[buf][(row * 4 + bu0) * 8]); } }

    // ================= 1) kv fused GEMM (16 chunks of K=32) ================
    f32x4 acck[2] = {}, accv[2] = {};
    LDA(xkv, 0); STA(0); STB(Wkb, BsA, 0, 0); STB(Wvb, BsB, 0, 0);
    LDA(xkv, 1);
    __syncthreads();

    for (int c = 0; c < 16; ++c) {
        if (c < 15) {
            STA((c + 1) & 1);
            STB(Wkb, BsA, c + 1, (c + 1) & 1);
            STB(Wvb, BsB, c + 1, (c + 1) & 1);
            if (c < 14) LDA(xkv, c + 2);
        }
        const unsigned short* as_ = As[c & 1];
        const unsigned short* bk_ = BsA[c & 1];
        const unsigned short* bv_ = BsB[c & 1];
        short8v a = *(const short8v*)&as_[frow * 40 + t16 * 8];
        #pragma unroll
        for (int nf = 0; nf < 2; ++nf) {
            int row = wv * 32 + nf * 16 + frow;
            int u = t16 ^ (row & 3);
            short8v bkf = *(const short8v*)&bk_[row * 32 + u * 8];
            short8v bvf = *(const short8v*)&bv_[row * 32 + u * 8];
            acck[nf] = __builtin_amdgcn_mfma_f32_16x16x32_bf16(a, bkf, acck[nf], 0, 0, 0);
            accv[nf] = __builtin_amdgcn_mfma_f32_16x16x32_bf16(a, bvf, accv[nf], 0, 0, 0);
        }
        __syncthreads();
    }

    // ================= 2) k,v -> overlay (+bias); moments ==================
    LDA(xq, 0);   // issue xq HBM loads early; latency hides under epilogue

    // C/D layout: col=lane&15, row=(lane>>4)*4+r  [m89-verified]
    #pragma unroll
    for (int nf = 0; nf < 2; ++nf) {
        int col = wv * 32 + nf * 16 + col_l;
        float bkc = bk[col], bvc = bv[col];
        #pragma unroll
        for (int r4 = 0; r4 < 4; ++r4) {
            int row = row_l + r4;
            k_lds[row * 128 + col] = acck[nf][r4] + bkc;
            v_lds[row * 128 + col] = accv[nf][r4] + bvc;
        }
    }
    STB(Wqb, BsA, 0, 0);   // BsA[0] free (kv reads done at final barrier)
    __syncthreads();       // overlay + Wq chunk-0 visible

    STA(0);                // As[0] <- xq chunk 0 (ra loaded pre-barrier)
    LDA(xq, 1);
    {   // moments: 16 threads/row (r = tid>>4, seg = tid&15)
        const int r = tid >> 4, seg = tid & 15;
        float s[7] = {};
        #pragma unroll
        for (int h = 0; h < 2; ++h) {
            float4 kf = *(const float4*)&k_lds[r * 128 + seg * 8 + h * 4];
            float4 vf = *(const float4*)&v_lds[r * 128 + seg * 8 + h * 4];
            float ke[4] = {kf.x, kf.y, kf.z, kf.w};
            float ve[4] = {vf.x, vf.y, vf.z, vf.w};
            #pragma unroll
            for (int e = 0; e < 4; ++e) {
                float k1 = ke[e], k2 = k1 * k1, k3 = k2 * k1, v1 = ve[e];
                s[0] += k1; s[1] += k2; s[2] += k3;
                s[3] += v1; s[4] += k1 * v1; s[5] += k2 * v1; s[6] += k3 * v1;
            }
        }
        #pragma unroll
        for (int off = 1; off <= 8; off <<= 1)
            #pragma unroll
            for (int t = 0; t < 7; ++t)
                s[t] += __shfl_xor(s[t], off, 64);
        if (seg == 0) {
            #pragma unroll
            for (int t = 0; t < 7; ++t) momp[r * 8 + t] = s[t];
        }
    }
    __syncthreads();       // moments + As[0] visible

    // ================= 3) q GEMM (16 chunks); x -> Xs ======================
    f32x4 accq[2] = {};
    for (int c = 0; c < 16; ++c) {
        if (c < 15) {
            STA((c + 1) & 1);
            STB(Wqb, BsA, c + 1, (c + 1) & 1);
            if (c < 14) LDA(xq, c + 2);
        }
        const unsigned short* as_ = As[c & 1];
        const unsigned short* bq_ = BsA[c & 1];
        short8v a = *(const short8v*)&as_[frow * 40 + t16 * 8];
        #pragma unroll
        for (int nf = 0; nf < 2; ++nf) {
            int row = wv * 32 + nf * 16 + frow;
            int u = t16 ^ (row & 3);
            short8v bf = *(const short8v*)&bq_[row * 32 + u * 8];
            accq[nf] = __builtin_amdgcn_mfma_f32_16x16x32_bf16(a, bf, accq[nf], 0, 0, 0);
        }
        __syncthreads();
    }

    STBP(0, 0, 0);   // proj step-0 staging hides under x evaluation

    {   // x = N(a)/D(a); write bf16 Xs with XOR-8 swizzle (BsB overlay; k/v dead)
        float bqc[2];
        #pragma unroll
        for (int nf = 0; nf < 2; ++nf) bqc[nf] = bq[wv * 32 + nf * 16 + col_l];
        #pragma unroll
        for (int r4 = 0; r4 < 4; ++r4) {
            int row = row_l + r4;
            float sm0 = momp[row * 8 + 0], sm1 = momp[row * 8 + 1];
            float sm2 = momp[row * 8 + 2], sm3 = momp[row * 8 + 3];
            float sm4 = momp[row * 8 + 4], sm5 = momp[row * 8 + 5];
            float sm6 = momp[row * 8 + 6];
            float h2n = 0.5f * sm5, h3n = (1.0f / 6.0f) * sm6;
            float h2d = 0.5f * sm1, h3d = (1.0f / 6.0f) * sm2;
            #pragma unroll
            for (int nf = 0; nf < 2; ++nf) {
                int col = wv * 32 + nf * 16 + col_l;
                float aa = (accq[nf][r4] + bqc[nf]) * (1.0f / 128.0f);
                float xn = sm3 + aa * (sm4 + aa * (h2n + aa * h3n));
                float xd = 128.0f + aa * (sm0 + aa * (h2d + aa * h3d));
                float xv = xn * __builtin_amdgcn_rcpf(xd);
                Xs[row * 128 + (col ^ ((row & 7) << 3))] = f2bfu(xv);
            }
        }
    }
    __syncthreads();   // Xs visible; proj step-0 staged

    // ================= 4) proj GEMM: 4 n-groups x 4 k-chunks ===============
    f32x4 accp[2] = {};
    for (int s = 0; s < 16; ++s) {
        const int ng = s >> 2, c = s & 3;
        if (s < 15) STBP((s + 1) >> 2, (s + 1) & 3, (s + 1) & 1);
        const unsigned short* bp_ = BsA[s & 1];
        short8v a = *(const short8v*)&Xs[frow * 128
                     + ((c * 32 + t16 * 8) ^ ((frow & 7) << 3))];
        #pragma unroll
        for (int nf = 0; nf < 2; ++nf) {
            int row = wv * 32 + nf * 16 + frow;
            int u = t16 ^ (row & 3);
            short8v bf = *(const short8v*)&bp_[row * 32 + u * 8];
            accp[nf] = __builtin_amdgcn_mfma_f32_16x16x32_bf16(a, bf, accp[nf], 0, 0, 0);
        }
        if (c == 3) {
            #pragma unroll
            for (int nf = 0; nf < 2; ++nf) {
                int col = ng * 128 + wv * 32 + nf * 16 + col_l;
                float pbc = pb[col];
                #pragma unroll
                for (int r4 = 0; r4 < 4; ++r4)
                    out[(size_t)(m0 + row_l + r4) * 512 + col] = accp[nf][r4] + pbc;
                accp[nf] = (f32x4){0.0f, 0.0f, 0.0f, 0.0f};
            }
        }
        __syncthreads();
    }
#undef LDA
#undef STA
#undef STB
#undef STBP
}

// ---------------------------------------------------------------------------
extern "C" void kernel_launch(void* const* d_in, const int* in_sizes, int n_in,
                              void* d_out, int out_size, void* d_ws, size_t ws_size,
                              hipStream_t stream) {
    const float* x_q    = (const float*)d_in[0];
    const float* x_kv   = (const float*)d_in[1];
    const float* Wq_w   = (const float*)d_in[2];
    const float* Wq_b   = (const float*)d_in[3];
    const float* Wk_w   = (const float*)d_in[4];
    const float* Wk_b   = (const float*)d_in[5];
    const float* Wv_w   = (const float*)d_in[6];
    const float* Wv_b   = (const float*)d_in[7];
    const float* proj_w = (const float*)d_in[8];
    const float* proj_b = (const float*)d_in[9];
    float* out = (float*)d_out;

    unsigned short* Wbf = (unsigned short*)d_ws;   // 512 KB bf16 weights

    prep_kernel<<<dim3(32, 4), 256, 0, stream>>>(Wq_w, Wk_w, Wv_w, proj_w, Wbf);
    fused_kernel<<<dim3(NROWS / 16), 256, 0, stream>>>(
        x_q, x_kv, Wbf, Wq_b, Wk_b, Wv_b, proj_b, out);
}

// Round 15
// 32.576 us; speedup vs baseline: 1.1616x; 1.1616x over previous
//
#include <hip/hip_runtime.h>
#include <hip/hip_bf16.h>

constexpr int NROWS = 8192;

typedef __attribute__((ext_vector_type(8))) short short8v; // 8 bf16
typedef __attribute__((ext_vector_type(4))) float f32x4;   // MFMA acc

__device__ __forceinline__ unsigned cvt2(float lo, float hi) {
    __hip_bfloat162 h;
    h.x = __float2bfloat16(lo);
    h.y = __float2bfloat16(hi);
    union { __hip_bfloat162 h2; unsigned u; } cv; cv.h2 = h; return cv.u;
}
__device__ __forceinline__ unsigned short f2bfu(float x) {
    __hip_bfloat16 h = __float2bfloat16(x);
    union { __hip_bfloat16 b; unsigned short u; } cv; cv.b = h; return cv.u;
}
// async global->LDS, 16B per lane; LDS dest must be linear (base + lane*16)
__device__ __forceinline__ void gload16(const void* g, void* l) {
    __builtin_amdgcn_global_load_lds(
        (const __attribute__((address_space(1))) unsigned int*)g,
        (__attribute__((address_space(3))) unsigned int*)l,
        16, 0, 0);
}

// ---------------------------------------------------------------------------
// Prep: 4 weight matrices -> bf16, once.  (proven)
// ---------------------------------------------------------------------------
__global__ __launch_bounds__(256) void prep_kernel(
    const float* __restrict__ Wq, const float* __restrict__ Wk,
    const float* __restrict__ Wv, const float* __restrict__ Wp,
    unsigned short* __restrict__ out)
{
    const float* srcs[4] = {Wq, Wk, Wv, Wp};
    const float* s = srcs[blockIdx.y];
    unsigned short* d = out + (size_t)blockIdx.y * 65536;
    int idx = blockIdx.x * 256 + threadIdx.x;
    float4 a = ((const float4*)s)[idx * 2];
    float4 b = ((const float4*)s)[idx * 2 + 1];
    uint4 p;
    p.x = cvt2(a.x, a.y); p.y = cvt2(a.z, a.w);
    p.z = cvt2(b.x, b.y); p.w = cvt2(b.z, b.w);
    ((uint4*)d)[idx] = p;
}

// ---------------------------------------------------------------------------
// Fully-fused kernel v4 = R12 structure scaled to 32 rows at same occupancy.
// 256 blocks x 32 rows x 256 threads (2x2 waves, wave tile 16x64), BK=64.
// LDS 75776 B -> 2 blocks/CU. Weight L2 traffic 128 MB (half of R12).
// Phases: kv GEMM (8 chunks) -> k,v->LDS(+bias) + moments(8 thr/row) ->
// q GEMM (8 chunks; x = N/D in-register -> Xs) -> proj (4 ng x 2 c) -> out.
// Zero intermediate global traffic.
// ---------------------------------------------------------------------------
__global__ __launch_bounds__(256) void fused_kernel(
    const float* __restrict__ xq, const float* __restrict__ xkv,
    const unsigned short* __restrict__ Wbf,
    const float* __restrict__ bq, const float* __restrict__ bk,
    const float* __restrict__ bv, const float* __restrict__ pb,
    float* __restrict__ out)
{
    __shared__ __align__(16) char smem[75776];
    // 0     : As[2][32*72] bf16 A dbuf (9216 B)   | overlay later: Xs[32*128] bf16 (8192)
    // 9216  : BsA[2][128*64] bf16 (32768 B)        Wk / Wq / Wp dbuf
    // 41984 : BsB[2][128*64] bf16 (32768 B)        Wv dbuf
    //         overlay after kv: k_lds[32][128] f32 (16384) @41984,
    //                           v_lds[32][128] f32 (16384) @58368
    // 74752 : mom[32][8] f32 (1024 B)
    unsigned short (*As)[32 * 72]   = (unsigned short (*)[32 * 72])smem;
    unsigned short (*BsA)[128 * 64] = (unsigned short (*)[128 * 64])(smem + 9216);
    unsigned short (*BsB)[128 * 64] = (unsigned short (*)[128 * 64])(smem + 41984);
    float* k_lds = (float*)(smem + 41984);
    float* v_lds = (float*)(smem + 58368);
    unsigned short* Xs = (unsigned short*)smem;
    float* momp = (float*)(smem + 74752);

    const int m0 = blockIdx.x * 32;
    const int tid = threadIdx.x, lane = tid & 63;
    const int w = tid >> 6, wr = w >> 1, wc = w & 1;   // 2x2 wave grid
    const int brow0 = tid >> 3, bu = tid & 7;          // B stage coords
    const int frow = lane & 15, t16 = lane >> 4;
    const int col_l = frow, row_l = t16 * 4;

    const unsigned short* Wqb = Wbf;
    const unsigned short* Wkb = Wbf + 65536;
    const unsigned short* Wvb = Wbf + 2 * 65536;
    const unsigned short* Wpb = Wbf + 3 * 65536;

    float4 ra[2];

    // A: 32 rows x 64 k f32 per chunk; 512 float4s / 256 thr = 2 each
#define LDA(src, c) { _Pragma("unroll") for (int i = 0; i < 2; ++i) { \
      int idx = tid + i * 256; int row = idx >> 4, c4 = idx & 15; \
      ra[i] = *(const float4*)((src) + (size_t)(m0 + row) * 512 + (c) * 64 + c4 * 4); } }
#define STA(buf) { _Pragma("unroll") for (int i = 0; i < 2; ++i) { \
      int idx = tid + i * 256; int row = idx >> 4, c4 = idx & 15; \
      uint2 p; p.x = cvt2(ra[i].x, ra[i].y); p.y = cvt2(ra[i].z, ra[i].w); \
      *(uint2*)(&As[buf][row * 72 + c4 * 4]) = p; } }
    // B: 128 rows x 64 k bf16, swizzled gload_lds (R12-proven), 4 per thread
#define STB(Wm, Bsx, c, buf) { _Pragma("unroll") for (int i = 0; i < 4; ++i) { \
      int row = brow0 + i * 32; int su = bu ^ (row & 7); \
      gload16((Wm) + (size_t)row * 512 + (c) * 64 + su * 8, \
              &(Bsx)[buf][(row * 8 + bu) * 8]); } }
#define STBP(ng, c, buf) { _Pragma("unroll") for (int i = 0; i < 4; ++i) { \
      int row = brow0 + i * 32; int su = bu ^ (row & 7); \
      gload16(Wpb + (size_t)((ng) * 128 + row) * 128 + (c) * 64 + su * 8, \
              &BsA[buf][(row * 8 + bu) * 8]); } }

    // ================= 1) kv fused GEMM (8 chunks of K=64) =================
    f32x4 acck[4] = {}, accv[4] = {};
    LDA(xkv, 0); STA(0); STB(Wkb, BsA, 0, 0); STB(Wvb, BsB, 0, 0);
    LDA(xkv, 1);
    __syncthreads();

    for (int c = 0; c < 8; ++c) {
        if (c < 7) {
            STA((c + 1) & 1);
            STB(Wkb, BsA, c + 1, (c + 1) & 1);
            STB(Wvb, BsB, c + 1, (c + 1) & 1);
            if (c < 6) LDA(xkv, c + 2);
        }
        const unsigned short* as_ = As[c & 1];
        const unsigned short* bk_ = BsA[c & 1];
        const unsigned short* bv_ = BsB[c & 1];
        short8v a[2];
        #pragma unroll
        for (int kk = 0; kk < 2; ++kk)
            a[kk] = *(const short8v*)&as_[(wr * 16 + frow) * 72 + kk * 32 + t16 * 8];
        #pragma unroll
        for (int kk = 0; kk < 2; ++kk)
            #pragma unroll
            for (int nf = 0; nf < 4; ++nf) {
                int row = wc * 64 + nf * 16 + frow;
                int u = (kk * 4 + t16) ^ (row & 7);
                short8v bkf = *(const short8v*)&bk_[row * 64 + u * 8];
                short8v bvf = *(const short8v*)&bv_[row * 64 + u * 8];
                acck[nf] = __builtin_amdgcn_mfma_f32_16x16x32_bf16(a[kk], bkf, acck[nf], 0, 0, 0);
                accv[nf] = __builtin_amdgcn_mfma_f32_16x16x32_bf16(a[kk], bvf, accv[nf], 0, 0, 0);
            }
        __syncthreads();
    }

    // ================= 2) k,v -> overlay (+bias); moments ==================
    LDA(xq, 0);   // issue xq HBM loads early; latency hides under epilogue

    // C/D layout: col=lane&15, row=(lane>>4)*4+r  [m89-verified]
    #pragma unroll
    for (int nf = 0; nf < 4; ++nf) {
        int col = wc * 64 + nf * 16 + col_l;
        float bkc = bk[col], bvc = bv[col];
        #pragma unroll
        for (int r4 = 0; r4 < 4; ++r4) {
            int row = wr * 16 + row_l + r4;
            k_lds[row * 128 + col] = acck[nf][r4] + bkc;
            v_lds[row * 128 + col] = accv[nf][r4] + bvc;
        }
    }
    STB(Wqb, BsA, 0, 0);   // BsA[0] free (kv frag reads done at final barrier)
    __syncthreads();       // overlay + Wq chunk-0 staged

    STA(0);                // As[0] <- xq chunk 0 (ra loaded pre-barrier)
    LDA(xq, 1);
    {   // moments: 8 threads/row (r = tid>>3, seg = tid&7, 16 cols each)
        const int r = tid >> 3, seg = tid & 7;
        float s[7] = {};
        #pragma unroll
        for (int h = 0; h < 4; ++h) {
            float4 kf = *(const float4*)&k_lds[r * 128 + seg * 16 + h * 4];
            float4 vf = *(const float4*)&v_lds[r * 128 + seg * 16 + h * 4];
            float ke[4] = {kf.x, kf.y, kf.z, kf.w};
            float ve[4] = {vf.x, vf.y, vf.z, vf.w};
            #pragma unroll
            for (int e = 0; e < 4; ++e) {
                float k1 = ke[e], k2 = k1 * k1, k3 = k2 * k1, v1 = ve[e];
                s[0] += k1; s[1] += k2; s[2] += k3;
                s[3] += v1; s[4] += k1 * v1; s[5] += k2 * v1; s[6] += k3 * v1;
            }
        }
        #pragma unroll
        for (int off = 1; off <= 4; off <<= 1)
            #pragma unroll
            for (int t = 0; t < 7; ++t)
                s[t] += __shfl_xor(s[t], off, 64);
        if (seg == 0) {
            #pragma unroll
            for (int t = 0; t < 7; ++t) momp[r * 8 + t] = s[t];
        }
    }
    __syncthreads();       // moments + As[0] visible

    // ================= 3) q GEMM (8 chunks); x -> Xs =======================
    f32x4 accq[4] = {};
    for (int c = 0; c < 8; ++c) {
        if (c < 7) {
            STA((c + 1) & 1);
            STB(Wqb, BsA, c + 1, (c + 1) & 1);
            if (c < 6) LDA(xq, c + 2);
        }
        const unsigned short* as_ = As[c & 1];
        const unsigned short* bq_ = BsA[c & 1];
        short8v a[2];
        #pragma unroll
        for (int kk = 0; kk < 2; ++kk)
            a[kk] = *(const short8v*)&as_[(wr * 16 + frow) * 72 + kk * 32 + t16 * 8];
        #pragma unroll
        for (int kk = 0; kk < 2; ++kk)
            #pragma unroll
            for (int nf = 0; nf < 4; ++nf) {
                int row = wc * 64 + nf * 16 + frow;
                int u = (kk * 4 + t16) ^ (row & 7);
                short8v bf = *(const short8v*)&bq_[row * 64 + u * 8];
                accq[nf] = __builtin_amdgcn_mfma_f32_16x16x32_bf16(a[kk], bf, accq[nf], 0, 0, 0);
            }
        __syncthreads();
    }

    STBP(0, 0, 0);   // proj step-0 staging hides under x evaluation

    {   // x = N(a)/D(a); write bf16 Xs with XOR-8 swizzle (As region overlay)
        float bqc[4];
        #pragma unroll
        for (int nf = 0; nf < 4; ++nf) bqc[nf] = bq[wc * 64 + nf * 16 + col_l];
        #pragma unroll
        for (int r4 = 0; r4 < 4; ++r4) {
            int row = wr * 16 + row_l + r4;
            float sm0 = momp[row * 8 + 0], sm1 = momp[row * 8 + 1];
            float sm2 = momp[row * 8 + 2], sm3 = momp[row * 8 + 3];
            float sm4 = momp[row * 8 + 4], sm5 = momp[row * 8 + 5];
            float sm6 = momp[row * 8 + 6];
            float h2n = 0.5f * sm5, h3n = (1.0f / 6.0f) * sm6;
            float h2d = 0.5f * sm1, h3d = (1.0f / 6.0f) * sm2;
            #pragma unroll
            for (int nf = 0; nf < 4; ++nf) {
                int col = wc * 64 + nf * 16 + col_l;
                float aa = (accq[nf][r4] + bqc[nf]) * (1.0f / 128.0f);
                float xn = sm3 + aa * (sm4 + aa * (h2n + aa * h3n));
                float xd = 128.0f + aa * (sm0 + aa * (h2d + aa * h3d));
                float xv = xn * __builtin_amdgcn_rcpf(xd);
                Xs[row * 128 + (col ^ ((row & 7) << 3))] = f2bfu(xv);
            }
        }
    }
    __syncthreads();   // Xs visible; proj step-0 staged

    // ================= 4) proj GEMM: 4 n-groups x 2 k-chunks ===============
    f32x4 accp[4] = {};
    for (int s = 0; s < 8; ++s) {
        const int ng = s >> 1, c = s & 1;
        if (s < 7) STBP((s + 1) >> 1, (s + 1) & 1, (s + 1) & 1);
        const unsigned short* bp_ = BsA[s & 1];
        short8v a[2];
        #pragma unroll
        for (int kk = 0; kk < 2; ++kk) {
            int arow_ = wr * 16 + frow;
            a[kk] = *(const short8v*)&Xs[arow_ * 128
                     + ((c * 64 + kk * 32 + t16 * 8) ^ ((arow_ & 7) << 3))];
        }
        #pragma unroll
        for (int kk = 0; kk < 2; ++kk)
            #pragma unroll
            for (int nf = 0; nf < 4; ++nf) {
                int row = wc * 64 + nf * 16 + frow;
                int u = (kk * 4 + t16) ^ (row & 7);
                short8v bf = *(const short8v*)&bp_[row * 64 + u * 8];
                accp[nf] = __builtin_amdgcn_mfma_f32_16x16x32_bf16(a[kk], bf, accp[nf], 0, 0, 0);
            }
        if (c == 1) {
            #pragma unroll
            for (int nf = 0; nf < 4; ++nf) {
                int col = ng * 128 + wc * 64 + nf * 16 + col_l;
                float pbc = pb[col];
                #pragma unroll
                for (int r4 = 0; r4 < 4; ++r4)
                    out[(size_t)(m0 + wr * 16 + row_l + r4) * 512 + col] = accp[nf][r4] + pbc;
                accp[nf] = (f32x4){0.0f, 0.0f, 0.0f, 0.0f};
            }
        }
        __syncthreads();
    }
#undef LDA
#undef STA
#undef STB
#undef STBP
}

// ---------------------------------------------------------------------------
extern "C" void kernel_launch(void* const* d_in, const int* in_sizes, int n_in,
                              void* d_out, int out_size, void* d_ws, size_t ws_size,
                              hipStream_t stream) {
    const float* x_q    = (const float*)d_in[0];
    const float* x_kv   = (const float*)d_in[1];
    const float* Wq_w   = (const float*)d_in[2];
    const float* Wq_b   = (const float*)d_in[3];
    const float* Wk_w   = (const float*)d_in[4];
    const float* Wk_b   = (const float*)d_in[5];
    const float* Wv_w   = (const float*)d_in[6];
    const float* Wv_b   = (const float*)d_in[7];
    const float* proj_w = (const float*)d_in[8];
    const float* proj_b = (const float*)d_in[9];
    float* out = (float*)d_out;

    unsigned short* Wbf = (unsigned short*)d_ws;   // 512 KB bf16 weights

    prep_kernel<<<dim3(32, 4), 256, 0, stream>>>(Wq_w, Wk_w, Wv_w, proj_w, Wbf);
    fused_kernel<<<dim3(NROWS / 32), 256, 0, stream>>>(
        x_q, x_kv, Wbf, Wq_b, Wk_b, Wv_b, proj_b, out);
}

// Round 16
// 30.674 us; speedup vs baseline: 1.2336x; 1.0620x over previous
//
#include <hip/hip_runtime.h>
#include <hip/hip_bf16.h>

constexpr int NROWS = 8192;

typedef __attribute__((ext_vector_type(8))) short short8v; // 8 bf16
typedef __attribute__((ext_vector_type(4))) float f32x4;   // MFMA acc

__device__ __forceinline__ unsigned cvt2(float lo, float hi) {
    __hip_bfloat162 h;
    h.x = __float2bfloat16(lo);
    h.y = __float2bfloat16(hi);
    union { __hip_bfloat162 h2; unsigned u; } cv; cv.h2 = h; return cv.u;
}
__device__ __forceinline__ unsigned short f2bfu(float x) {
    __hip_bfloat16 h = __float2bfloat16(x);
    union { __hip_bfloat16 b; unsigned short u; } cv; cv.b = h; return cv.u;
}
// async global->LDS, 16B per lane; LDS dest must be linear (base + lane*16)
__device__ __forceinline__ void gload16(const void* g, void* l) {
    __builtin_amdgcn_global_load_lds(
        (const __attribute__((address_space(1))) unsigned int*)g,
        (__attribute__((address_space(3))) unsigned int*)l,
        16, 0, 0);
}

// ---------------------------------------------------------------------------
// Prep: convert the 4 weight matrices (each 65536 f32) to bf16 once.
// ---------------------------------------------------------------------------
__global__ __launch_bounds__(256) void prep_kernel(
    const float* __restrict__ Wq, const float* __restrict__ Wk,
    const float* __restrict__ Wv, const float* __restrict__ Wp,
    unsigned short* __restrict__ out)
{
    const float* srcs[4] = {Wq, Wk, Wv, Wp};
    const float* s = srcs[blockIdx.y];
    unsigned short* d = out + (size_t)blockIdx.y * 65536;
    int idx = blockIdx.x * 256 + threadIdx.x;
    float4 a = ((const float4*)s)[idx * 2];
    float4 b = ((const float4*)s)[idx * 2 + 1];
    uint4 p;
    p.x = cvt2(a.x, a.y); p.y = cvt2(a.z, a.w);
    p.z = cvt2(b.x, b.y); p.w = cvt2(b.z, b.w);
    ((uint4*)d)[idx] = p;
}

// ---------------------------------------------------------------------------
// Fully-fused block kernel (R12, measured-best 30.7 us): 512 blocks x 16 rows,
// 256 threads, no global sync, no intermediate global traffic.  Per block:
//   1) k,v fused GEMM (K=512, shared x_kv A-tile, dbuf gload_lds B)
//   2) k,v (f32 + bias) -> LDS; 7 Taylor moments/row (16 thr/row shfl reduce)
//   3) q GEMM; epilogue evaluates x = N(a)/D(a) in-register -> Xs bf16
//      (XOR-8 swizzle)
//   4) proj GEMM (4 n-groups of 128 cols, dbuf), writes out rows m0..m0+16
// LDS 70656 B -> 2 blocks/CU co-resident.
// Bracketing scan (R13/R14/R15): every neighbor (rows x2, BK/2, occupancy x2)
// regresses -> this is the local optimum of the family.
// ---------------------------------------------------------------------------
__global__ __launch_bounds__(256, 1) void fused_kernel(
    const float* __restrict__ xq, const float* __restrict__ xkv,
    const unsigned short* __restrict__ Wbf,
    const float* __restrict__ bq, const float* __restrict__ bk,
    const float* __restrict__ bv, const float* __restrict__ pb,
    float* __restrict__ out)
{
    __shared__ __align__(16) char smem[70656];
    // 0     : As[2][16*72] bf16 A dbuf (4608 B)
    // 4608  : BsA[2][128*64] bf16 (32768 B)   Wk / Wq / Wp dbuf
    // 37376 : BsB[2][128*64] bf16 (32768 B)   Wv dbuf
    //         overlay after kv GEMM: k_lds[16][132] f32 (8448),
    //         v_lds[16][132] f32 (8448), Xs[16*128] bf16 (4096)
    // 70144 : moments[16][8] f32 (512 B)
    unsigned short (*As)[16 * 72]   = (unsigned short (*)[16 * 72])smem;
    unsigned short (*BsA)[128 * 64] = (unsigned short (*)[128 * 64])(smem + 4608);
    unsigned short (*BsB)[128 * 64] = (unsigned short (*)[128 * 64])(smem + 37376);
    float* k_lds = (float*)(smem + 37376);
    float* v_lds = (float*)(smem + 37376 + 8448);
    unsigned short* Xs = (unsigned short*)(smem + 37376 + 16896);
    float* momp = (float*)(smem + 70144);

    const int m0 = blockIdx.x * 16;
    const int tid = threadIdx.x, lane = tid & 63;
    const int wv = tid >> 6;                    // wave -> col group wv*32
    const int arow = tid >> 4, ac4 = tid & 15;  // A stage coords
    const int brow0 = tid >> 3, bu = tid & 7;   // B stage coords
    const int frow = lane & 15, t16 = lane >> 4;
    const int col_l = frow, row_l = t16 * 4;

    const unsigned short* Wqb = Wbf;
    const unsigned short* Wkb = Wbf + 65536;
    const unsigned short* Wvb = Wbf + 2 * 65536;
    const unsigned short* Wpb = Wbf + 3 * 65536;

    float4 ra;

#define LDA(src, c) ra = *(const float4*)((src) + (size_t)(m0 + arow) * 512 + (c) * 64 + ac4 * 4);
#define STA(buf) { uint2 p; p.x = cvt2(ra.x, ra.y); p.y = cvt2(ra.z, ra.w); \
                   *(uint2*)(&As[buf][arow * 72 + ac4 * 4]) = p; }
#define STB(Wm, Bsx, c, buf) { _Pragma("unroll") for (int i = 0; i < 4; ++i) { \
      int row = brow0 + i * 32; int su = bu ^ (row & 7); \
      gload16((Wm) + (size_t)row * 512 + (c) * 64 + su * 8, &(Bsx)[buf][(row * 8 + bu) * 8]); } }
#define STBP(ng, c, buf) { _Pragma("unroll") for (int i = 0; i < 4; ++i) { \
      int row = brow0 + i * 32; int su = bu ^ (row & 7); \
      gload16(Wpb + (size_t)((ng) * 128 + row) * 128 + (c) * 64 + su * 8, \
              &BsA[buf][(row * 8 + bu) * 8]); } }

    // ================= 1) kv fused GEMM (K=512, 8 chunks) ==================
    f32x4 acck[2] = {}, accv[2] = {};
    LDA(xkv, 0); STA(0); STB(Wkb, BsA, 0, 0); STB(Wvb, BsB, 0, 0);
    LDA(xkv, 1);
    __syncthreads();

    for (int c = 0; c < 8; ++c) {
        if (c < 7) {
            STA((c + 1) & 1);
            STB(Wkb, BsA, c + 1, (c + 1) & 1);
            STB(Wvb, BsB, c + 1, (c + 1) & 1);
            if (c < 6) LDA(xkv, c + 2);
        }
        const unsigned short* as_ = As[c & 1];
        const unsigned short* bk_ = BsA[c & 1];
        const unsigned short* bv_ = BsB[c & 1];
        short8v a[2], bkf[2][2], bvf[2][2];
        #pragma unroll
        for (int kk = 0; kk < 2; ++kk) {
            a[kk] = *(const short8v*)&as_[frow * 72 + kk * 32 + t16 * 8];
            #pragma unroll
            for (int nf = 0; nf < 2; ++nf) {
                int row = wv * 32 + nf * 16 + frow;
                int u = (kk * 4 + t16) ^ (row & 7);
                bkf[nf][kk] = *(const short8v*)&bk_[row * 64 + u * 8];
                bvf[nf][kk] = *(const short8v*)&bv_[row * 64 + u * 8];
            }
        }
        #pragma unroll
        for (int kk = 0; kk < 2; ++kk)
            #pragma unroll
            for (int nf = 0; nf < 2; ++nf) {
                acck[nf] = __builtin_amdgcn_mfma_f32_16x16x32_bf16(a[kk], bkf[nf][kk], acck[nf], 0, 0, 0);
                accv[nf] = __builtin_amdgcn_mfma_f32_16x16x32_bf16(a[kk], bvf[nf][kk], accv[nf], 0, 0, 0);
            }
        __syncthreads();
    }

    // ================= 2) k,v -> LDS (f32+bias); moments ===================
    // C/D layout: col=lane&15, row=(lane>>4)*4+r  [m89-verified]
    #pragma unroll
    for (int nf = 0; nf < 2; ++nf) {
        int col = wv * 32 + nf * 16 + col_l;
        float bkc = bk[col], bvc = bv[col];
        #pragma unroll
        for (int r4 = 0; r4 < 4; ++r4) {
            int row = row_l + r4;
            k_lds[row * 132 + col] = acck[nf][r4] + bkc;
            v_lds[row * 132 + col] = accv[nf][r4] + bvc;
        }
    }
    __syncthreads();

    // issue q chunk-0 staging now: latency hides under the moments math
    f32x4 accq[2] = {};
    LDA(xq, 0); STA(0); STB(Wqb, BsA, 0, 0);
    LDA(xq, 1);

    {   // moments: 16 threads/row (tid>>4 = row, tid&15 = 8-col segment)
        const int r = tid >> 4, seg = tid & 15;
        float s[7] = {};
        #pragma unroll
        for (int j = 0; j < 8; ++j) {
            float k1 = k_lds[r * 132 + seg * 8 + j];
            float v1 = v_lds[r * 132 + seg * 8 + j];
            float k2 = k1 * k1, k3 = k2 * k1;
            s[0] += k1; s[1] += k2; s[2] += k3;
            s[3] += v1; s[4] += k1 * v1; s[5] += k2 * v1; s[6] += k3 * v1;
        }
        #pragma unroll
        for (int off = 1; off <= 8; off <<= 1)
            #pragma unroll
            for (int t = 0; t < 7; ++t)
                s[t] += __shfl_xor(s[t], off, 64);
        if (seg == 0) {
            #pragma unroll
            for (int t = 0; t < 7; ++t) momp[r * 8 + t] = s[t];
        }
    }
    __syncthreads();   // moments visible; q chunk-0 staged

    // ================= 3) q GEMM; epilogue -> x -> Xs ======================
    for (int c = 0; c < 8; ++c) {
        if (c < 7) {
            STA((c + 1) & 1);
            STB(Wqb, BsA, c + 1, (c + 1) & 1);
            if (c < 6) LDA(xq, c + 2);
        }
        const unsigned short* as_ = As[c & 1];
        const unsigned short* bq_ = BsA[c & 1];
        short8v a[2], bf[2][2];
        #pragma unroll
        for (int kk = 0; kk < 2; ++kk) {
            a[kk] = *(const short8v*)&as_[frow * 72 + kk * 32 + t16 * 8];
            #pragma unroll
            for (int nf = 0; nf < 2; ++nf) {
                int row = wv * 32 + nf * 16 + frow;
                int u = (kk * 4 + t16) ^ (row & 7);
                bf[nf][kk] = *(const short8v*)&bq_[row * 64 + u * 8];
            }
        }
        #pragma unroll
        for (int kk = 0; kk < 2; ++kk)
            #pragma unroll
            for (int nf = 0; nf < 2; ++nf)
                accq[nf] = __builtin_amdgcn_mfma_f32_16x16x32_bf16(a[kk], bf[nf][kk], accq[nf], 0, 0, 0);
        __syncthreads();
    }

    STBP(0, 0, 0);   // proj step-0 staging hides under x evaluation

    {   // x = N(a)/D(a) from accq + moments; write bf16 Xs (XOR-8 swizzle)
        float bqc[2];
        #pragma unroll
        for (int nf = 0; nf < 2; ++nf) bqc[nf] = bq[wv * 32 + nf * 16 + col_l];
        #pragma unroll
        for (int r4 = 0; r4 < 4; ++r4) {
            int row = row_l + r4;
            float sm0 = momp[row * 8 + 0], sm1 = momp[row * 8 + 1];
            float sm2 = momp[row * 8 + 2], sm3 = momp[row * 8 + 3];
            float sm4 = momp[row * 8 + 4], sm5 = momp[row * 8 + 5];
            float sm6 = momp[row * 8 + 6];
            float h2n = 0.5f * sm5, h3n = (1.0f / 6.0f) * sm6;
            float h2d = 0.5f * sm1, h3d = (1.0f / 6.0f) * sm2;
            #pragma unroll
            for (int nf = 0; nf < 2; ++nf) {
                int col = wv * 32 + nf * 16 + col_l;
                float aa = (accq[nf][r4] + bqc[nf]) * (1.0f / 128.0f);
                float xn = sm3 + aa * (sm4 + aa * (h2n + aa * h3n));
                float xd = 128.0f + aa * (sm0 + aa * (h2d + aa * h3d));
                float xv = xn * __builtin_amdgcn_rcpf(xd);
                Xs[row * 128 + (col ^ ((row & 7) << 3))] = f2bfu(xv);
            }
        }
    }
    __syncthreads();   // Xs visible; proj step-0 staged

    // ================= 4) proj GEMM: 4 n-groups x 2 k-chunks ===============
    f32x4 accp[2] = {};
    for (int s = 0; s < 8; ++s) {
        const int ng = s >> 1, c = s & 1;
        if (s < 7) STBP((s + 1) >> 1, (s + 1) & 1, (s + 1) & 1);
        const unsigned short* bp_ = BsA[s & 1];
        short8v a[2], bf[2][2];
        #pragma unroll
        for (int kk = 0; kk < 2; ++kk) {
            a[kk] = *(const short8v*)&Xs[frow * 128
                     + ((c * 64 + kk * 32 + t16 * 8) ^ ((frow & 7) << 3))];
            #pragma unroll
            for (int nf = 0; nf < 2; ++nf) {
                int row = wv * 32 + nf * 16 + frow;
                int u = (kk * 4 + t16) ^ (row & 7);
                bf[nf][kk] = *(const short8v*)&bp_[row * 64 + u * 8];
            }
        }
        #pragma unroll
        for (int kk = 0; kk < 2; ++kk)
            #pragma unroll
            for (int nf = 0; nf < 2; ++nf)
                accp[nf] = __builtin_amdgcn_mfma_f32_16x16x32_bf16(a[kk], bf[nf][kk], accp[nf], 0, 0, 0);
        if (c == 1) {   // end of this n-group: write out + reset acc
            #pragma unroll
            for (int nf = 0; nf < 2; ++nf) {
                int col = ng * 128 + wv * 32 + nf * 16 + col_l;
                float pbc = pb[col];
                #pragma unroll
                for (int r4 = 0; r4 < 4; ++r4)
                    out[(size_t)(m0 + row_l + r4) * 512 + col] = accp[nf][r4] + pbc;
                accp[nf] = (f32x4){0.0f, 0.0f, 0.0f, 0.0f};
            }
        }
        __syncthreads();
    }
#undef LDA
#undef STA
#undef STB
#undef STBP
}

// ---------------------------------------------------------------------------
extern "C" void kernel_launch(void* const* d_in, const int* in_sizes, int n_in,
                              void* d_out, int out_size, void* d_ws, size_t ws_size,
                              hipStream_t stream) {
    const float* x_q    = (const float*)d_in[0];
    const float* x_kv   = (const float*)d_in[1];
    const float* Wq_w   = (const float*)d_in[2];
    const float* Wq_b   = (const float*)d_in[3];
    const float* Wk_w   = (const float*)d_in[4];
    const float* Wk_b   = (const float*)d_in[5];
    const float* Wv_w   = (const float*)d_in[6];
    const float* Wv_b   = (const float*)d_in[7];
    const float* proj_w = (const float*)d_in[8];
    const float* proj_b = (const float*)d_in[9];
    float* out = (float*)d_out;

    unsigned short* Wbf = (unsigned short*)d_ws;   // 512 KB bf16 weights

    prep_kernel<<<dim3(32, 4), 256, 0, stream>>>(Wq_w, Wk_w, Wv_w, proj_w, Wbf);
    fused_kernel<<<dim3(NROWS / 16), 256, 0, stream>>>(
        x_q, x_kv, Wbf, Wq_b, Wk_b, Wv_b, proj_b, out);
}